// Round 1
// baseline (1994.912 us; speedup 1.0000x reference)
//
#include <hip/hip_runtime.h>
#include <hip/hip_bf16.h>
#include <math.h>

// Tree-LSTM "LogicEncoder": D=10, N=1023 nodes, B=128, LD=256, K=2.
// Strategy:
//  - Pack per-level gate weights into Wbig (768 x 1024): rows = [x | hL | hR],
//    col groups = [i | u | f0 | f1]; bias packed likewise. Leaves: Wleaf (256 x 512) = [Wcx | Wox].
//  - h/c stored node-major (node_local, b, d) so children of node w are slots 2w, 2w+1.
//  - One fused GEMM+LSTM-epilogue kernel per level (9 serial levels), ping-pong buffers.
//  - fp32 everywhere this round (correctness first; no fp32 MFMA on CDNA4).

#define NNODES 1023
#define BATCH  128
#define LDIM   256

__device__ __forceinline__ float fast_sigmoid(float x) {
    return 1.f / (1.f + __expf(-x));
}
__device__ __forceinline__ float fast_tanh(float x) {
    float xc = fminf(fmaxf(x, -15.f), 15.f);
    float e = __expf(2.f * xc);
    return (e - 1.f) / (e + 1.f);
}

// ---------------------------------------------------------------------------
// Pack Wbig (768x1024) + bias_big(1024) + Wleaf(256x512) + bias_leaf(512).
__global__ __launch_bounds__(256) void build_weights(
    const float* __restrict__ Wix, const float* __restrict__ bix,
    const float* __restrict__ Wfx, const float* __restrict__ bfx,
    const float* __restrict__ Wux, const float* __restrict__ bux,
    const float* __restrict__ Wi,  const float* __restrict__ bi,
    const float* __restrict__ Wf,  const float* __restrict__ bf,
    const float* __restrict__ Wu,  const float* __restrict__ bu,
    const float* __restrict__ Wcx, const float* __restrict__ bcx,
    const float* __restrict__ Wox, const float* __restrict__ box,
    float* __restrict__ Wbig, float* __restrict__ bias_big,
    float* __restrict__ Wleaf, float* __restrict__ bias_leaf)
{
    int i = blockIdx.x * blockDim.x + threadIdx.x;
    if (i < 768 * 1024) {
        int k = i >> 10, n = i & 1023;
        int g = n >> 8, nn = n & 255;
        float v;
        if (g == 0) {
            v = (k < 256) ? Wix[k * 256 + nn]
              : (k < 512) ? Wi[(k - 256) * 256 + nn]
                          : Wi[65536 + (k - 512) * 256 + nn];
        } else if (g == 1) {
            v = (k < 256) ? Wux[k * 256 + nn]
              : (k < 512) ? Wu[(k - 256) * 256 + nn]
                          : Wu[65536 + (k - 512) * 256 + nn];
        } else {
            int kf = g - 2;  // f0 / f1
            v = (k < 256) ? Wfx[k * 256 + nn]
              : (k < 512) ? Wf[((kf * 2 + 0) * 256 + (k - 256)) * 256 + nn]
                          : Wf[((kf * 2 + 1) * 256 + (k - 512)) * 256 + nn];
        }
        Wbig[i] = v;
        return;
    }
    i -= 768 * 1024;
    if (i < 1024) {
        int g = i >> 8, nn = i & 255;
        float v;
        if (g == 0)      v = bix[nn] + bi[nn] + bi[256 + nn];
        else if (g == 1) v = bux[nn] + bu[nn] + bu[256 + nn];
        else if (g == 2) v = bfx[nn] + bf[nn] + bf[256 + nn];          // bf[0,0]+bf[0,1]
        else             v = bfx[nn] + bf[512 + nn] + bf[768 + nn];    // bf[1,0]+bf[1,1]
        bias_big[i] = v;
        return;
    }
    i -= 1024;
    if (i < 256 * 512) {
        int k = i >> 9, n = i & 511;
        Wleaf[i] = (n < 256) ? Wcx[k * 256 + n] : Wox[k * 256 + (n - 256)];
        return;
    }
    i -= 256 * 512;
    if (i < 512) {
        bias_leaf[i] = (i < 256) ? bcx[i] : box[i - 256];
    }
}

// ---------------------------------------------------------------------------
// Leaf kernel: rows r = w*128+b (w=leaf local 0..511), A = x_embed row (K=256),
// 2 col groups (c = Wcx cols, o = Wox cols), fused h/c epilogue.
// grid (1024, 4), block 256.
__global__ __launch_bounds__(256) void leaf_kernel(
    const float* __restrict__ x_embed,
    const float* __restrict__ Wleaf, const float* __restrict__ bias_leaf,
    float* __restrict__ hOut, float* __restrict__ cOut)
{
    __shared__ float As[16 * 68];      // [kk][row], stride 68 (16B-aligned rows, low conflicts)
    __shared__ float Bs[2 * 16 * 64];  // [g][kk][n]
    float acc[2][4][4] = {};
    const int tid = threadIdx.x;
    const int ty = tid >> 4, tx = tid & 15;
    const int row0 = blockIdx.x * 64;
    const int n0 = blockIdx.y * 64;
    const int w = row0 >> 7;               // uniform per block
    const int ar = tid >> 2;               // 0..63 (row within tile)
    const int kq = (tid & 3) * 4;          // k chunk
    const int b = (row0 + ar) & 127;
    const float* xrow = x_embed + ((size_t)b * NNODES + 511 + w) * LDIM;

    for (int k0 = 0; k0 < 256; k0 += 16) {
        float4 av = *(const float4*)(xrow + k0 + kq);
        As[(kq + 0) * 68 + ar] = av.x;
        As[(kq + 1) * 68 + ar] = av.y;
        As[(kq + 2) * 68 + ar] = av.z;
        As[(kq + 3) * 68 + ar] = av.w;
#pragma unroll
        for (int q = 0; q < 2; ++q) {
            int L = q * 256 + tid;            // 0..511 float4 groups
            int g = L >> 8, kk = (L >> 4) & 15, n4 = (L & 15) * 4;
            float4 bv = *(const float4*)(Wleaf + (size_t)(k0 + kk) * 512 + g * 256 + n0 + n4);
            *(float4*)&Bs[(g * 16 + kk) * 64 + n4] = bv;
        }
        __syncthreads();
#pragma unroll
        for (int kk = 0; kk < 16; ++kk) {
            float4 a = *(const float4*)&As[kk * 68 + ty * 4];
            float av4[4] = {a.x, a.y, a.z, a.w};
#pragma unroll
            for (int g = 0; g < 2; ++g) {
                float4 bb = *(const float4*)&Bs[(g * 16 + kk) * 64 + tx * 4];
                float bv4[4] = {bb.x, bb.y, bb.z, bb.w};
#pragma unroll
                for (int ii = 0; ii < 4; ++ii)
#pragma unroll
                    for (int jj = 0; jj < 4; ++jj)
                        acc[g][ii][jj] += av4[ii] * bv4[jj];
            }
        }
        __syncthreads();
    }
#pragma unroll
    for (int ii = 0; ii < 4; ++ii) {
        int r = row0 + ty * 4 + ii;
        int nc = n0 + tx * 4;
        float4 c4, h4;
        float* cp = (float*)&c4; float* hp = (float*)&h4;
#pragma unroll
        for (int jj = 0; jj < 4; ++jj) {
            int n = nc + jj;
            float ac = acc[0][ii][jj] + bias_leaf[n];
            float ao = acc[1][ii][jj] + bias_leaf[256 + n];
            cp[jj] = ac;                                  // c_leaf = linear
            hp[jj] = fast_sigmoid(ao) * fast_tanh(ac);    // h_leaf
        }
        *(float4*)&cOut[(size_t)r * LDIM + nc] = c4;
        *(float4*)&hOut[(size_t)r * LDIM + nc] = h4;
    }
}

// ---------------------------------------------------------------------------
// Level kernel: rows r = w*128+b, A row = [x | hL | hR] (K=768), 4 col groups
// [i|u|f0|f1], fused LSTM epilogue c = sig(i)*tanh(u) + f0*cL + f1*cR, h = tanh(c).
// grid (W*2, 4), block 256.
__global__ __launch_bounds__(256) void level_kernel(
    const float* __restrict__ x_embed,
    const float* __restrict__ hChild, const float* __restrict__ cChild,
    const float* __restrict__ Wbig, const float* __restrict__ bias_big,
    float* __restrict__ hOut, float* __restrict__ cOut,
    int nstart)
{
    __shared__ float As[16 * 68];
    __shared__ float Bs[4 * 16 * 64];
    float acc[4][4][4] = {};
    const int tid = threadIdx.x;
    const int ty = tid >> 4, tx = tid & 15;
    const int row0 = blockIdx.x * 64;
    const int n0 = blockIdx.y * 64;
    const int w = row0 >> 7;               // uniform per block
    const int ar = tid >> 2;
    const int kq = (tid & 3) * 4;
    const int b = (row0 + ar) & 127;
    const float* srcX = x_embed + ((size_t)b * NNODES + nstart + w) * LDIM;
    const float* srcL = hChild + ((size_t)(2 * w) * BATCH + b) * LDIM;
    const float* srcR = hChild + ((size_t)(2 * w + 1) * BATCH + b) * LDIM;

    for (int k0 = 0; k0 < 768; k0 += 16) {
        int seg = k0 >> 8, off = k0 & 255;
        const float* src = (seg == 0) ? srcX : (seg == 1) ? srcL : srcR;
        float4 av = *(const float4*)(src + off + kq);
        As[(kq + 0) * 68 + ar] = av.x;
        As[(kq + 1) * 68 + ar] = av.y;
        As[(kq + 2) * 68 + ar] = av.z;
        As[(kq + 3) * 68 + ar] = av.w;
#pragma unroll
        for (int q = 0; q < 4; ++q) {
            int L = q * 256 + tid;            // 0..1023 float4 groups
            int g = L >> 8, kk = (L >> 4) & 15, n4 = (L & 15) * 4;
            float4 bv = *(const float4*)(Wbig + (size_t)(k0 + kk) * 1024 + g * 256 + n0 + n4);
            *(float4*)&Bs[(g * 16 + kk) * 64 + n4] = bv;
        }
        __syncthreads();
#pragma unroll
        for (int kk = 0; kk < 16; ++kk) {
            float4 a = *(const float4*)&As[kk * 68 + ty * 4];
            float av4[4] = {a.x, a.y, a.z, a.w};
#pragma unroll
            for (int g = 0; g < 4; ++g) {
                float4 bb = *(const float4*)&Bs[(g * 16 + kk) * 64 + tx * 4];
                float bv4[4] = {bb.x, bb.y, bb.z, bb.w};
#pragma unroll
                for (int ii = 0; ii < 4; ++ii)
#pragma unroll
                    for (int jj = 0; jj < 4; ++jj)
                        acc[g][ii][jj] += av4[ii] * bv4[jj];
            }
        }
        __syncthreads();
    }
    const size_t cLbase = ((size_t)(2 * w) * BATCH) * LDIM;
    const size_t cRbase = ((size_t)(2 * w + 1) * BATCH) * LDIM;
#pragma unroll
    for (int ii = 0; ii < 4; ++ii) {
        int r = row0 + ty * 4 + ii;
        int bb2 = r & 127;
        int nc = n0 + tx * 4;
        float4 cL = *(const float4*)&cChild[cLbase + (size_t)bb2 * LDIM + nc];
        float4 cR = *(const float4*)&cChild[cRbase + (size_t)bb2 * LDIM + nc];
        float cl4[4] = {cL.x, cL.y, cL.z, cL.w};
        float cr4[4] = {cR.x, cR.y, cR.z, cR.w};
        float4 c4, h4;
        float* cp = (float*)&c4; float* hp = (float*)&h4;
#pragma unroll
        for (int jj = 0; jj < 4; ++jj) {
            int n = nc + jj;
            float ai = acc[0][ii][jj] + bias_big[n];
            float au = acc[1][ii][jj] + bias_big[256 + n];
            float f0 = acc[2][ii][jj] + bias_big[512 + n];
            float f1 = acc[3][ii][jj] + bias_big[768 + n];
            float c = fast_sigmoid(ai) * fast_tanh(au) + f0 * cl4[jj] + f1 * cr4[jj];
            cp[jj] = c;
            hp[jj] = fast_tanh(c);
        }
        *(float4*)&cOut[(size_t)r * LDIM + nc] = c4;
        *(float4*)&hOut[(size_t)r * LDIM + nc] = h4;
    }
}

// ---------------------------------------------------------------------------
// Final: out[b][n] = tanh([init | c_root | h_root] @ Woend + boend). grid 128, block 256.
__global__ __launch_bounds__(256) void final_kernel(
    const float* __restrict__ init_emb,
    const float* __restrict__ cRoot, const float* __restrict__ hRoot,
    const float* __restrict__ Woend, const float* __restrict__ boend,
    float* __restrict__ out)
{
    __shared__ float sv[768];
    int b = blockIdx.x, t = threadIdx.x;
    sv[t]       = init_emb[(size_t)b * 256 + t];
    sv[256 + t] = cRoot[(size_t)b * 256 + t];
    sv[512 + t] = hRoot[(size_t)b * 256 + t];
    __syncthreads();
    float acc = boend[t];
#pragma unroll 4
    for (int d = 0; d < 768; ++d)
        acc += sv[d] * Woend[(size_t)d * 256 + t];
    out[(size_t)b * 256 + t] = fast_tanh(acc);
}

// ---------------------------------------------------------------------------
extern "C" void kernel_launch(void* const* d_in, const int* in_sizes, int n_in,
                              void* d_out, int out_size, void* d_ws, size_t ws_size,
                              hipStream_t stream)
{
    const float* x_embed  = (const float*)d_in[0];
    const float* init_emb = (const float*)d_in[1];
    const float* Wcx = (const float*)d_in[2];  const float* bcx = (const float*)d_in[3];
    const float* Wox = (const float*)d_in[4];  const float* box = (const float*)d_in[5];
    const float* Wix = (const float*)d_in[6];  const float* bix = (const float*)d_in[7];
    const float* Wfx = (const float*)d_in[8];  const float* bfx = (const float*)d_in[9];
    const float* Wux = (const float*)d_in[10]; const float* bux = (const float*)d_in[11];
    const float* Wi  = (const float*)d_in[12]; const float* bi  = (const float*)d_in[13];
    const float* Wf  = (const float*)d_in[14]; const float* bf  = (const float*)d_in[15];
    const float* Wu  = (const float*)d_in[16]; const float* bu  = (const float*)d_in[17];
    const float* Woend = (const float*)d_in[18]; const float* boend = (const float*)d_in[19];
    float* out = (float*)d_out;
    float* ws  = (float*)d_ws;

    size_t off = 0;
    float* hA = ws + off; off += (size_t)512 * 128 * 256;   // 64 MB: leaf/even-level h
    float* cA = ws + off; off += (size_t)512 * 128 * 256;
    float* hB = ws + off; off += (size_t)256 * 128 * 256;   // 32 MB
    float* cB = ws + off; off += (size_t)256 * 128 * 256;
    float* Wbig      = ws + off; off += (size_t)768 * 1024;
    float* bias_big  = ws + off; off += 1024;
    float* Wleaf     = ws + off; off += (size_t)256 * 512;
    float* bias_leaf = ws + off; off += 512;

    {
        int total = 768 * 1024 + 1024 + 256 * 512 + 512;
        int blocks = (total + 255) / 256;
        build_weights<<<blocks, 256, 0, stream>>>(
            Wix, bix, Wfx, bfx, Wux, bux, Wi, bi, Wf, bf, Wu, bu,
            Wcx, bcx, Wox, box, Wbig, bias_big, Wleaf, bias_leaf);
    }

    leaf_kernel<<<dim3(1024, 4), 256, 0, stream>>>(x_embed, Wleaf, bias_leaf, hA, cA);

    float* hbufs[2] = {hA, hB};
    float* cbufs[2] = {cA, cB};
    int child = 0;  // leaves in A
    for (int lvl = 8; lvl >= 0; --lvl) {
        int W = 1 << lvl, s = W - 1;
        int outb = child ^ 1;
        level_kernel<<<dim3(W * 2, 4), 256, 0, stream>>>(
            x_embed, hbufs[child], cbufs[child], Wbig, bias_big,
            hbufs[outb], cbufs[outb], s);
        child = outb;
    }

    final_kernel<<<128, 256, 0, stream>>>(init_emb, cbufs[child], hbufs[child],
                                          Woend, boend, out);
}